// Round 1
// baseline (347.664 us; speedup 1.0000x reference)
//
#include <hip/hip_runtime.h>

// Correlation1dCost: out[b,d,y,x] = leaky_relu_0.1( sum_c f1[b,c,y,x]*f2[b,c,y,x+d-47] )
// B=8, C=128, H=128, W=256, ND=48. Zero contribution where x+d-47 < 0.

#define Bn 8
#define Cn 128
#define Hn 128
#define Wn 256
#define ND 48
#define PAD 48           // LDS f2 buffer starts at shift index -48 (16B aligned)
#define F2LEN 304        // covers shifted x in [-48, 255]
#define CC 8             // channels staged per iteration
#define TD 12            // d's per thread
// thread layout: 64 x-groups (4 x each) x 4 d-groups (12 d each) = 256 threads

__global__ __launch_bounds__(256, 4)
void corr1d_kernel(const float* __restrict__ f1,
                   const float* __restrict__ f2,
                   float* __restrict__ out)
{
    __shared__ float s1[CC][Wn];     // 8 KB
    __shared__ float s2[CC][F2LEN];  // 9.5 KB

    const int y   = blockIdx.x;      // 0..127
    const int b   = blockIdx.y;      // 0..7
    const int tid = threadIdx.x;
    const int i   = tid & 63;        // x-group: x = 4*i .. 4*i+3
    const int j   = tid >> 6;        // d-group: d = 12*j .. 12*j+11

    const size_t chw = (size_t)Hn * Wn;                 // channel stride
    const float* f1base = f1 + ((size_t)b * Cn * Hn + y) * Wn;
    const float* f2base = f2 + ((size_t)b * Cn * Hn + y) * Wn;

    float acc[4][TD];
    #pragma unroll
    for (int xr = 0; xr < 4; ++xr)
        #pragma unroll
        for (int dr = 0; dr < TD; ++dr) acc[xr][dr] = 0.f;

    for (int c0 = 0; c0 < Cn; c0 += CC) {
        // ---- stage f1: CC rows x 64 float4 = 512 float4, 2 per thread ----
        #pragma unroll
        for (int rep = 0; rep < 2; ++rep) {
            int lin = tid + rep * 256;          // [0,512)
            int cl  = lin >> 6;
            int p4  = lin & 63;
            float4 v = *(const float4*)(f1base + (size_t)(c0 + cl) * chw + p4 * 4);
            *(float4*)&s1[cl][p4 * 4] = v;
        }
        // ---- stage f2: CC rows x 76 float4 (first 12 are the zero pad) ----
        for (int lin = tid; lin < CC * 76; lin += 256) {
            int cl = lin / 76;
            int p4 = lin - cl * 76;
            int s4 = p4 * 4 - PAD;              // shifted-x of first float
            float4 v = make_float4(0.f, 0.f, 0.f, 0.f);
            if (s4 >= 0)
                v = *(const float4*)(f2base + (size_t)(c0 + cl) * chw + s4);
            *(float4*)&s2[cl][p4 * 4] = v;
        }
        __syncthreads();

        // ---- compute: per channel, 1+4 b128 LDS reads, 48 FMAs ----
        #pragma unroll
        for (int cc = 0; cc < CC; ++cc) {
            const int base = i * 4 + j * TD;    // max 252+36=288; +15 <= 303
            float a[4], q[16];
            *(float4*)&a[0]  = *(const float4*)&s1[cc][i * 4];
            *(float4*)&q[0]  = *(const float4*)&s2[cc][base];
            *(float4*)&q[4]  = *(const float4*)&s2[cc][base + 4];
            *(float4*)&q[8]  = *(const float4*)&s2[cc][base + 8];
            *(float4*)&q[12] = *(const float4*)&s2[cc][base + 12];
            // out x = 4i+xr, d = 12j+dr -> shifted idx (4i+xr)+(12j+dr)-47,
            // buffer-relative = xr+dr+1  (buffer starts at -48)
            #pragma unroll
            for (int xr = 0; xr < 4; ++xr)
                #pragma unroll
                for (int dr = 0; dr < TD; ++dr)
                    acc[xr][dr] += a[xr] * q[xr + dr + 1];
        }
        __syncthreads();
    }

    // ---- epilogue: leaky_relu + float4 stores (contiguous per wave) ----
    #pragma unroll
    for (int dr = 0; dr < TD; ++dr) {
        int d = j * TD + dr;
        float vx[4];
        #pragma unroll
        for (int xr = 0; xr < 4; ++xr) {
            float t = acc[xr][dr];
            vx[xr] = t >= 0.f ? t : 0.1f * t;
        }
        float4 v = make_float4(vx[0], vx[1], vx[2], vx[3]);
        *(float4*)(out + (((size_t)(b * ND + d) * Hn + y) * Wn + i * 4)) = v;
    }
}

extern "C" void kernel_launch(void* const* d_in, const int* in_sizes, int n_in,
                              void* d_out, int out_size, void* d_ws, size_t ws_size,
                              hipStream_t stream) {
    const float* feat1 = (const float*)d_in[0];
    const float* feat2 = (const float*)d_in[1];
    float* out = (float*)d_out;
    dim3 grid(Hn, Bn);   // blockIdx.x = y, blockIdx.y = b
    dim3 block(256);
    corr1d_kernel<<<grid, block, 0, stream>>>(feat1, feat2, out);
}

// Round 2
// 339.867 us; speedup vs baseline: 1.0229x; 1.0229x over previous
//
#include <hip/hip_runtime.h>

// Correlation1dCost: out[b,d,y,x] = leaky_relu_0.1( sum_c f1[b,c,y,x]*f2[b,c,y,x+d-47] )
// B=8, C=128, H=128, W=256, ND=48. Zero contribution where x+d-47 < 0.
//
// R2: __launch_bounds__(256,2) — R1's (256,4) made the compiler squeeze to 64
// VGPRs by scalarizing the float4 LDS loads into ds_read_b32 (lane-stride 4
// words -> 8-way bank conflict, SQ_LDS_BANK_CONFLICT=5e7). With a 256-VGPR
// budget the b128 loads survive and conflicts vanish.

#define Bn 8
#define Cn 128
#define Hn 128
#define Wn 256
#define ND 48
#define PAD 48           // LDS f2 buffer starts at shift index -48 (16B aligned)
#define F2LEN 304        // covers shifted x in [-48, 255]
#define CC 8             // channels staged per iteration
#define TD 12            // d's per thread
// thread layout: 64 x-groups (4 x each) x 4 d-groups (12 d each) = 256 threads

__global__ __launch_bounds__(256, 2)
void corr1d_kernel(const float* __restrict__ f1,
                   const float* __restrict__ f2,
                   float* __restrict__ out)
{
    __shared__ float s1[CC][Wn];     // 8 KB
    __shared__ float s2[CC][F2LEN];  // 9.5 KB

    const int y   = blockIdx.x;      // 0..127
    const int b   = blockIdx.y;      // 0..7
    const int tid = threadIdx.x;
    const int i   = tid & 63;        // x-group: x = 4*i .. 4*i+3
    const int j   = tid >> 6;        // d-group: d = 12*j .. 12*j+11
    const int base = i * 4 + j * TD; // q window start (16B aligned); max 288, +15 <= 303

    const size_t chw = (size_t)Hn * Wn;                 // channel stride
    const float* f1base = f1 + ((size_t)b * Cn * Hn + y) * Wn;
    const float* f2base = f2 + ((size_t)b * Cn * Hn + y) * Wn;

    float acc[4][TD];
    #pragma unroll
    for (int xr = 0; xr < 4; ++xr)
        #pragma unroll
        for (int dr = 0; dr < TD; ++dr) acc[xr][dr] = 0.f;

    for (int c0 = 0; c0 < Cn; c0 += CC) {
        // ---- stage f1: CC rows x 64 float4 = 512 float4, 2 per thread ----
        #pragma unroll
        for (int rep = 0; rep < 2; ++rep) {
            int lin = tid + rep * 256;          // [0,512)
            int cl  = lin >> 6;
            int p4  = lin & 63;
            float4 v = *(const float4*)(f1base + (size_t)(c0 + cl) * chw + p4 * 4);
            *(float4*)&s1[cl][p4 * 4] = v;
        }
        // ---- stage f2: CC rows x 76 float4 (first 12 are the zero pad) ----
        // flat word address == lin*4, so writes are fully contiguous.
        for (int lin = tid; lin < CC * 76; lin += 256) {
            int cl = lin / 76;
            int p4 = lin - cl * 76;
            int s4 = p4 * 4 - PAD;              // shifted-x of first float
            float4 v = make_float4(0.f, 0.f, 0.f, 0.f);
            if (s4 >= 0)
                v = *(const float4*)(f2base + (size_t)(c0 + cl) * chw + s4);
            *(float4*)&s2[cl][p4 * 4] = v;
        }
        __syncthreads();

        // ---- compute: per channel, 1+4 ds_read_b128, 48 FMAs ----
        #pragma unroll
        for (int cc = 0; cc < CC; ++cc) {
            float4 av = *(const float4*)&s1[cc][i * 4];
            float4 q0 = *(const float4*)&s2[cc][base];
            float4 q1 = *(const float4*)&s2[cc][base + 4];
            float4 q2 = *(const float4*)&s2[cc][base + 8];
            float4 q3 = *(const float4*)&s2[cc][base + 12];
            float a[4] = {av.x, av.y, av.z, av.w};
            float q[16] = {q0.x, q0.y, q0.z, q0.w,
                           q1.x, q1.y, q1.z, q1.w,
                           q2.x, q2.y, q2.z, q2.w,
                           q3.x, q3.y, q3.z, q3.w};
            // out x = 4i+xr, d = 12j+dr -> shifted idx (4i+xr)+(12j+dr)-47,
            // buffer-relative = xr+dr+1  (buffer starts at -48)
            #pragma unroll
            for (int xr = 0; xr < 4; ++xr)
                #pragma unroll
                for (int dr = 0; dr < TD; ++dr)
                    acc[xr][dr] += a[xr] * q[xr + dr + 1];
        }
        __syncthreads();
    }

    // ---- epilogue: leaky_relu + float4 stores (contiguous per wave) ----
    #pragma unroll
    for (int dr = 0; dr < TD; ++dr) {
        int d = j * TD + dr;
        float vx[4];
        #pragma unroll
        for (int xr = 0; xr < 4; ++xr) {
            float t = acc[xr][dr];
            vx[xr] = t >= 0.f ? t : 0.1f * t;
        }
        float4 v = make_float4(vx[0], vx[1], vx[2], vx[3]);
        *(float4*)(out + (((size_t)(b * ND + d) * Hn + y) * Wn + i * 4)) = v;
    }
}

extern "C" void kernel_launch(void* const* d_in, const int* in_sizes, int n_in,
                              void* d_out, int out_size, void* d_ws, size_t ws_size,
                              hipStream_t stream) {
    const float* feat1 = (const float*)d_in[0];
    const float* feat2 = (const float*)d_in[1];
    float* out = (float*)d_out;
    dim3 grid(Hn, Bn);   // blockIdx.x = y, blockIdx.y = b
    dim3 block(256);
    corr1d_kernel<<<grid, block, 0, stream>>>(feat1, feat2, out);
}